// Round 1
// baseline (988.924 us; speedup 1.0000x reference)
//
#include <hip/hip_runtime.h>
#include <hip/hip_bf16.h>

#define NTOT  1048576
#define MWG   256          // rows per workgroup
#define BLK   256          // threads (4 waves)
#define ROWB  384          // act row stride in bytes (192 bf16)
#define ACT_BYTES  (MWG * ROWB)          // 98304
#define WBUF_BYTES 49152                 // max chunk: 128n x 192k bf16
#define LDS_BYTES  (ACT_BYTES + WBUF_BYTES)   // 147456

typedef __attribute__((ext_vector_type(8))) short  bf16x8;
typedef __attribute__((ext_vector_type(4))) float  f32x4;

__device__ __forceinline__ unsigned short f2bf(float f) {
  unsigned u = __float_as_uint(f);
  u += 0x7fffu + ((u >> 16) & 1u);          // RNE
  return (unsigned short)(u >> 16);
}

// ---------------- weight prepack: fp32 -> bf16, W^T [n][k], concat-reordered, zero-padded ----------------
__global__ __launch_bounds__(256) void prepack_k(
    const float* __restrict__ s0, const float* __restrict__ s1,
    const float* __restrict__ s2, const float* __restrict__ s3,
    const float* __restrict__ s4, const float* __restrict__ s5,
    const float* __restrict__ s6, const float* __restrict__ s7,
    const float* __restrict__ s8, const float* __restrict__ s9,
    const float* __restrict__ s10, unsigned short* __restrict__ dst)
{
  // chunks: b1_w0, b1_w1..4, b2_w0, b2_w1, b2_w2, b2_w3, b3_w0, b3_w1
  const int nw_[11]  = {128,128,128,128,128,128,128,128,144, 64, 16};
  const int kw_[11]  = { 64,128,128,128,128,192,128,128,128,192, 64};
  const int nc_[11]  = {128,128,128,128,128,128,128,128,129, 64,  3};
  const int k1_[11]  = { 63,128,128,128,128, 63,128,128,128, 27, 64}; // k<k1 -> src row o1+k
  const int o1_[11]  = {  0,  0,  0,  0,  0,128,  0,  0,  0,128,  0};
  const int k2_[11]  = {999,999,999,999,999, 64,999,999,999, 64,999}; // k>=k2 -> src row k-k2
  const int do_[11]  = {0,8192,24576,40960,57344,73728,98304,114688,131072,149504,161792};

  int c = blockIdx.x;
  const float* src =
    c==0?s0: c==1?s1: c==2?s2: c==3?s3: c==4?s4: c==5?s5:
    c==6?s6: c==7?s7: c==8?s8: c==9?s9: s10;
  int nw=nw_[c], kw=kw_[c], nc=nc_[c], k1=k1_[c], o1=o1_[c], k2=k2_[c];
  int total = nw * kw;
  for (int idx = blockIdx.y * blockDim.x + threadIdx.x; idx < total;
       idx += gridDim.y * blockDim.x) {
    int n = idx / kw;
    int k = idx - n * kw;
    float v = 0.f;
    if (n < nc) {
      if (k < k1)       v = src[(o1 + k) * nc + n];
      else if (k >= k2) v = src[(k - k2) * nc + n];
    }
    dst[do_[c] + idx] = f2bf(v);
  }
}

// ---------------- main fused kernel ----------------
__device__ __forceinline__ void stageW(unsigned char* wlb,
                                       const unsigned short* __restrict__ wp,
                                       int woff, int nw, int kw, int tid)
{
  int total = nw * kw;
  for (int idx = tid * 8; idx < total; idx += BLK * 8) {
    uint4 v = *(const uint4*)(wp + woff + idx);
    int n = idx / kw;
    int k = idx - n * kw;
    int byt = n * (kw * 2) + k * 2;
    byt ^= (n & 7) << 4;                 // bank-conflict swizzle
    *(uint4*)(wlb + byt) = v;
  }
}

// write 64 bf16 cols (cols 0..63) of one act row, swizzled
__device__ __forceinline__ void write_row64(unsigned char* actb, int row, const float* f)
{
#pragma unroll
  for (int q = 0; q < 8; q++) {
    unsigned short h[8];
#pragma unroll
    for (int i = 0; i < 8; i++) h[i] = f2bf(f[q * 8 + i]);
    uint4 v;
    v.x = (unsigned)h[0] | ((unsigned)h[1] << 16);
    v.y = (unsigned)h[2] | ((unsigned)h[3] << 16);
    v.z = (unsigned)h[4] | ((unsigned)h[5] << 16);
    v.w = (unsigned)h[6] | ((unsigned)h[7] << 16);
    int b = row * ROWB + q * 16;
    b ^= (row & 7) << 4;
    *(uint4*)(actb + b) = v;
  }
}

// One layer: D[n][m] = sum_k Wt[n][k] * act[m][KB+k]; epilogue writes act (or outputs).
// MODE 0: relu -> act.  MODE 1: b2_w3 (feat no-relu -> act, nt==8 is sigma tile -> out).
// MODE 2: b3_w1 (sigmoid -> color out).
template<int KS, int NT, int MODE, int KW, int KB, int DST>
__device__ __attribute__((noinline)) void layer_f(
    unsigned char* actb, unsigned char* wlb, int mbase, int lane,
    float* __restrict__ out, long grow0)
{
  const int l15 = lane & 15;
  const int lg  = lane >> 4;
  const f32x4 vzero = {0.f, 0.f, 0.f, 0.f};
  f32x4 acc[4][NT];
#pragma unroll
  for (int a = 0; a < 4; a++)
#pragma unroll
    for (int b = 0; b < NT; b++) acc[a][b] = vzero;

#pragma unroll
  for (int ks = 0; ks < KS; ks++) {
    const int kloc = ks * 32 + lg * 8;
    bf16x8 bfr[4];
#pragma unroll
    for (int mt = 0; mt < 4; mt++) {
      int m = mbase + mt * 16 + l15;
      int byt = m * ROWB + (KB + kloc) * 2;
      byt ^= (m & 7) << 4;
      bfr[mt] = *(const bf16x8*)(actb + byt);
    }
    bf16x8 afr[NT];
#pragma unroll
    for (int nt = 0; nt < NT; nt++) {
      int n = nt * 16 + l15;
      int byt = n * (KW * 2) + kloc * 2;
      byt ^= (n & 7) << 4;
      afr[nt] = *(const bf16x8*)(wlb + byt);
    }
#pragma unroll
    for (int nt = 0; nt < NT; nt++)
#pragma unroll
      for (int mt = 0; mt < 4; mt++)
        acc[mt][nt] = __builtin_amdgcn_mfma_f32_16x16x32_bf16(
            afr[nt], bfr[mt], acc[mt][nt], 0, 0, 0);
  }

#pragma unroll
  for (int mt = 0; mt < 4; mt++) {
    int m = mbase + mt * 16 + l15;
#pragma unroll
    for (int nt = 0; nt < NT; nt++) {
      f32x4 v = acc[mt][nt];
      if (MODE == 1 && nt == 8) {               // sigma column (n==128 -> lg==0, reg 0)
        if (lg == 0) out[3L * NTOT + grow0 + m] = fmaxf(v.x, 0.f);
      } else if (MODE == 2) {                   // color, n=0..2 -> lg==0 regs 0..2
        if (lg == 0) {
          long g3 = (grow0 + m) * 3;
          out[g3 + 0] = 1.f / (1.f + __expf(-v.x));
          out[g3 + 1] = 1.f / (1.f + __expf(-v.y));
          out[g3 + 2] = 1.f / (1.f + __expf(-v.z));
        }
      } else {
        if (MODE == 0) {
          v.x = fmaxf(v.x, 0.f); v.y = fmaxf(v.y, 0.f);
          v.z = fmaxf(v.z, 0.f); v.w = fmaxf(v.w, 0.f);
        }
        unsigned short h0 = f2bf(v.x), h1 = f2bf(v.y), h2 = f2bf(v.z), h3 = f2bf(v.w);
        uint2 pk;
        pk.x = (unsigned)h0 | ((unsigned)h1 << 16);
        pk.y = (unsigned)h2 | ((unsigned)h3 << 16);
        int col = DST + nt * 16 + lg * 4;       // 4 consecutive features at fixed row
        int byt = m * ROWB + col * 2;
        byt ^= (m & 7) << 4;
        *(uint2*)(actb + byt) = pk;
      }
    }
  }
}

__global__ __launch_bounds__(BLK, 1) void nerf_fused(
    const float* __restrict__ pos, const float* __restrict__ dirs,
    const unsigned short* __restrict__ wp, float* __restrict__ out)
{
  extern __shared__ unsigned char lds[];
  unsigned char* actb = lds;                 // act[256][192] bf16, swizzled rows
  unsigned char* wlb  = lds + ACT_BYTES;     // current layer W^T, swizzled rows

  const int tid   = threadIdx.x;
  const int lane  = tid & 63;
  const int mbase = (tid >> 6) * 64;         // wave owns 64 rows end-to-end
  const long grow0 = (long)blockIdx.x * MWG;

  // posenc(pos) -> cols 0..62, col 63 = 0
  {
    long g = grow0 + tid;
    float p0 = pos[g * 3 + 0], p1 = pos[g * 3 + 1], p2 = pos[g * 3 + 2];
    float f[64];
    f[0] = p0; f[1] = p1; f[2] = p2;
    float s0 = p0, s1 = p1, s2 = p2;
#pragma unroll
    for (int j = 0; j < 10; j++) {
      f[3 + 6 * j + 0] = __sinf(s0); f[3 + 6 * j + 1] = __sinf(s1); f[3 + 6 * j + 2] = __sinf(s2);
      f[3 + 6 * j + 3] = __cosf(s0); f[3 + 6 * j + 4] = __cosf(s1); f[3 + 6 * j + 5] = __cosf(s2);
      s0 *= 2.f; s1 *= 2.f; s2 *= 2.f;
    }
    f[63] = 0.f;
    write_row64(actb, tid, f);
  }

  // b1_w0: x_emb(K=64) -> h (cols 64..191)
  stageW(wlb, wp, 0, 128, 64, tid);  __syncthreads();
  layer_f<2, 8, 0, 64, 0, 64>(actb, wlb, mbase, lane, out, grow0);
  // b1_w1..b1_w4
  __syncthreads(); stageW(wlb, wp, 8192, 128, 128, tid);  __syncthreads();
  layer_f<4, 8, 0, 128, 64, 64>(actb, wlb, mbase, lane, out, grow0);
  __syncthreads(); stageW(wlb, wp, 24576, 128, 128, tid); __syncthreads();
  layer_f<4, 8, 0, 128, 64, 64>(actb, wlb, mbase, lane, out, grow0);
  __syncthreads(); stageW(wlb, wp, 40960, 128, 128, tid); __syncthreads();
  layer_f<4, 8, 0, 128, 64, 64>(actb, wlb, mbase, lane, out, grow0);
  __syncthreads(); stageW(wlb, wp, 57344, 128, 128, tid); __syncthreads();
  layer_f<4, 8, 0, 128, 64, 64>(actb, wlb, mbase, lane, out, grow0);
  // b2_w0: K=192 over [x_emb | h] (rows reordered in prepack)
  __syncthreads(); stageW(wlb, wp, 73728, 128, 192, tid); __syncthreads();
  layer_f<6, 8, 0, 192, 0, 64>(actb, wlb, mbase, lane, out, grow0);

  // posenc(dirs) -> cols 0..26, cols 27..63 = 0 (x_emb dead now; own-wave rows only)
  {
    long g = grow0 + tid;
    float p0 = dirs[g * 3 + 0], p1 = dirs[g * 3 + 1], p2 = dirs[g * 3 + 2];
    float f[64];
#pragma unroll
    for (int i = 0; i < 64; i++) f[i] = 0.f;
    f[0] = p0; f[1] = p1; f[2] = p2;
    float s0 = p0, s1 = p1, s2 = p2;
#pragma unroll
    for (int j = 0; j < 4; j++) {
      f[3 + 6 * j + 0] = __sinf(s0); f[3 + 6 * j + 1] = __sinf(s1); f[3 + 6 * j + 2] = __sinf(s2);
      f[3 + 6 * j + 3] = __cosf(s0); f[3 + 6 * j + 4] = __cosf(s1); f[3 + 6 * j + 5] = __cosf(s2);
      s0 *= 2.f; s1 *= 2.f; s2 *= 2.f;
    }
    write_row64(actb, tid, f);
  }

  // b2_w1, b2_w2
  __syncthreads(); stageW(wlb, wp, 98304, 128, 128, tid);  __syncthreads();
  layer_f<4, 8, 0, 128, 64, 64>(actb, wlb, mbase, lane, out, grow0);
  __syncthreads(); stageW(wlb, wp, 114688, 128, 128, tid); __syncthreads();
  layer_f<4, 8, 0, 128, 64, 64>(actb, wlb, mbase, lane, out, grow0);
  // b2_w3: feat (no relu) + sigma tile
  __syncthreads(); stageW(wlb, wp, 131072, 144, 128, tid); __syncthreads();
  layer_f<4, 9, 1, 128, 64, 64>(actb, wlb, mbase, lane, out, grow0);
  // b3_w0: K=192 over [d_emb | feat] -> c1 (cols 0..63)
  __syncthreads(); stageW(wlb, wp, 149504, 64, 192, tid);  __syncthreads();
  layer_f<6, 4, 0, 192, 0, 0>(actb, wlb, mbase, lane, out, grow0);
  // b3_w1: K=64 -> color
  __syncthreads(); stageW(wlb, wp, 161792, 16, 64, tid);   __syncthreads();
  layer_f<2, 1, 2, 64, 0, 0>(actb, wlb, mbase, lane, out, grow0);
}

extern "C" void kernel_launch(void* const* d_in, const int* in_sizes, int n_in,
                              void* d_out, int out_size, void* d_ws, size_t ws_size,
                              hipStream_t stream)
{
  const float* pos  = (const float*)d_in[0];
  const float* dirs = (const float*)d_in[1];
  unsigned short* wpack = (unsigned short*)d_ws;   // 325,632 B used
  float* out = (float*)d_out;

  (void)hipFuncSetAttribute((const void*)nerf_fused,
                            hipFuncAttributeMaxDynamicSharedMemorySize, LDS_BYTES);

  prepack_k<<<dim3(11, 8, 1), 256, 0, stream>>>(
      (const float*)d_in[2], (const float*)d_in[3], (const float*)d_in[4],
      (const float*)d_in[5], (const float*)d_in[6], (const float*)d_in[7],
      (const float*)d_in[8], (const float*)d_in[9], (const float*)d_in[10],
      (const float*)d_in[11], (const float*)d_in[12], wpack);

  nerf_fused<<<NTOT / MWG, BLK, LDS_BYTES, stream>>>(pos, dirs, wpack, out);
}